// Round 1
// baseline (359.423 us; speedup 1.0000x reference)
//
#include <hip/hip_runtime.h>

// DTI WLS fit -> FA, with exact replication of the reference's SymEig noise:
//   noise = 1e-6 * jax.random.normal(key(42), (100,100,100,3,3), f32)
// JAX threefry (partitionable path, modern default): 32-bit draw for element
// idx = second output of threefry2x32(key=(0,42), counter=(idx>>32, idx&0xffffffff)).
// normal = sqrt(2) * erfinv(u*2 + lo), lo = nextafter(-1,0) = -0.99999994,
// u = bitcast((bits>>9)|0x3f800000) - 1, clamped with max(lo, .).
// erfinv = XLA's Giles polynomial (exact constants).

__device__ __forceinline__ unsigned tf_rotl(unsigned x, int r) {
  return (x << r) | (x >> (32 - r));
}

// Threefry-2x32, 20 rounds, key (0, 42); returns SECOND output word.
__device__ __forceinline__ unsigned threefry_second(unsigned x0, unsigned x1) {
  const unsigned k0 = 0u, k1 = 42u;
  const unsigned k2 = 0x1BD11BDAu ^ k0 ^ k1;
  x0 += k0; x1 += k1;
#define TF_ROUND(r) { x0 += x1; x1 = tf_rotl(x1, r); x1 ^= x0; }
  TF_ROUND(13) TF_ROUND(15) TF_ROUND(26) TF_ROUND(6)
  x0 += k1; x1 += k2 + 1u;
  TF_ROUND(17) TF_ROUND(29) TF_ROUND(16) TF_ROUND(24)
  x0 += k2; x1 += k0 + 2u;
  TF_ROUND(13) TF_ROUND(15) TF_ROUND(26) TF_ROUND(6)
  x0 += k0; x1 += k1 + 3u;
  TF_ROUND(17) TF_ROUND(29) TF_ROUND(16) TF_ROUND(24)
  x0 += k1; x1 += k2 + 4u;
  TF_ROUND(13) TF_ROUND(15) TF_ROUND(26) TF_ROUND(6)
  x0 += k2; x1 += k0 + 5u;
#undef TF_ROUND
  (void)x0;
  return x1;
}

// XLA ErfInv32 (Giles), exact constants.
__device__ __forceinline__ float erfinv_xla(float x) {
  float w = -__logf(fmaf(-x, x, 1.0f));
  float p;
  if (w < 5.0f) {
    w = w - 2.5f;
    p = 2.81022636e-08f;
    p = fmaf(p, w, 3.43273939e-07f);
    p = fmaf(p, w, -3.5233877e-06f);
    p = fmaf(p, w, -4.39150654e-06f);
    p = fmaf(p, w, 0.00021858087f);
    p = fmaf(p, w, -0.00125372503f);
    p = fmaf(p, w, -0.00417768164f);
    p = fmaf(p, w, 0.246640727f);
    p = fmaf(p, w, 1.50140941f);
  } else {
    w = __builtin_sqrtf(w) - 3.0f;
    p = -0.000200214257f;
    p = fmaf(p, w, 0.000100950558f);
    p = fmaf(p, w, 0.00134934322f);
    p = fmaf(p, w, -0.00367342844f);
    p = fmaf(p, w, 0.00573950773f);
    p = fmaf(p, w, -0.0076224613f);
    p = fmaf(p, w, 0.00943887047f);
    p = fmaf(p, w, 1.00167406f);
    p = fmaf(p, w, 2.83297682f);
  }
  return p * x;
}

__device__ __forceinline__ float jax_normal_at(unsigned idx) {
  unsigned bits = threefry_second(0u, idx);   // counter hi = 0 (idx < 2^32)
  float f = __uint_as_float((bits >> 9) | 0x3F800000u);  // [1,2)
  float u = f - 1.0f;                                    // [0,1)
  const float lo = -0.99999994f;                          // nextafter(-1,0)
  float val = fmaf(u, 2.0f, lo);                          // (hi-lo) rounds to 2.0f
  val = fmaxf(lo, val);
  return 1.41421356237f * erfinv_xla(val);                // sqrt(2) in f32
}

#define NG 64

__global__ __launch_bounds__(256) void fa_kernel(
    const float* __restrict__ dwi,
    const float* __restrict__ mask,
    const float* __restrict__ W,     // [7,64], rows 0..5 used
    const float* __restrict__ mdp,   // scalar min_diffusivity
    float* __restrict__ out,
    int nvox)
{
  int v = blockIdx.x * 256 + threadIdx.x;
  if (v >= nvox) return;
  const float md = mdp[0];

  // ---- matvec: fit[i] = sum_j W[i][j] * log(max(dwi[v][j], md)) ----
  const float4* __restrict__ p =
      reinterpret_cast<const float4*>(dwi + (size_t)v * NG);
  float f0 = 0.f, f1 = 0.f, f2 = 0.f, f3 = 0.f, f4 = 0.f, f5 = 0.f;
#pragma unroll
  for (int j4 = 0; j4 < NG / 4; ++j4) {
    float4 d = p[j4];
    float xs[4];
    xs[0] = __logf(fmaxf(d.x, md));
    xs[1] = __logf(fmaxf(d.y, md));
    xs[2] = __logf(fmaxf(d.z, md));
    xs[3] = __logf(fmaxf(d.w, md));
#pragma unroll
    for (int k = 0; k < 4; ++k) {
      int j = j4 * 4 + k;
      float x = xs[k];
      f0 = fmaf(W[0 * NG + j], x, f0);
      f1 = fmaf(W[1 * NG + j], x, f1);
      f2 = fmaf(W[2 * NG + j], x, f2);
      f3 = fmaf(W[3 * NG + j], x, f3);
      f4 = fmaf(W[4 * NG + j], x, f4);
      f5 = fmaf(W[5 * NG + j], x, f5);
    }
  }

  // ---- tensor (LT_INDICES): [[f0,f1,f3],[f1,f2,f4],[f3,f4,f5]] + noise, symmetrized ----
  unsigned base = 9u * (unsigned)v;
  float z[9];
#pragma unroll
  for (int e = 0; e < 9; ++e) z[e] = jax_normal_at(base + (unsigned)e);

  const float eps = 1e-6f;
  float a00 = f0 + eps * z[0];
  float a11 = f2 + eps * z[4];
  float a22 = f5 + eps * z[8];
  float a01 = ((f1 + eps * z[1]) + (f1 + eps * z[3])) * 0.5f;
  float a02 = ((f3 + eps * z[2]) + (f3 + eps * z[6])) * 0.5f;
  float a12 = ((f4 + eps * z[5]) + (f4 + eps * z[7])) * 0.5f;

  // ---- closed-form symmetric 3x3 eigenvalues (trigonometric method) ----
  float q = (a00 + a11 + a22) * (1.0f / 3.0f);
  float aa = a00 - q, bb = a11 - q, cc = a22 - q;
  float p2 = aa * aa + bb * bb + cc * cc +
             2.0f * (a01 * a01 + a02 * a02 + a12 * a12);
  float pp = __builtin_sqrtf(p2 * (1.0f / 6.0f));
  float invp = (pp > 0.0f) ? (1.0f / pp) : 0.0f;
  float b00 = aa * invp, b11 = bb * invp, b22 = cc * invp;
  float b01 = a01 * invp, b02 = a02 * invp, b12 = a12 * invp;
  float detB = b00 * (b11 * b22 - b12 * b12)
             - b01 * (b01 * b22 - b12 * b02)
             + b02 * (b01 * b12 - b11 * b02);
  float r = 0.5f * detB;
  r = fminf(1.0f, fmaxf(-1.0f, r));
  float phi = acosf(r) * (1.0f / 3.0f);
  float l0 = q + 2.0f * pp * cosf(phi);
  float l2 = q + 2.0f * pp * cosf(phi + 2.0943951023931953f); // +2pi/3
  float l1 = 3.0f * q - l0 - l2;

  // ---- clamp, FA ----
  l0 = fmaxf(l0, md);
  l1 = fmaxf(l1, md);
  l2 = fmaxf(l2, md);
  float d01 = l0 - l1, d12 = l1 - l2, d20 = l2 - l0;
  float num = 0.5f * (d01 * d01 + d12 * d12 + d20 * d20);
  float den = l0 * l0 + l1 * l1 + l2 * l2;  // >= 3*md^2 > 0, all_zero impossible
  float fa = __builtin_sqrtf(num / den);

  out[v] = fa * mask[v];
}

extern "C" void kernel_launch(void* const* d_in, const int* in_sizes, int n_in,
                              void* d_out, int out_size, void* d_ws, size_t ws_size,
                              hipStream_t stream) {
  const float* dwi  = (const float*)d_in[0];
  const float* mask = (const float*)d_in[1];
  const float* W    = (const float*)d_in[2];
  const float* mdp  = (const float*)d_in[3];
  float* out = (float*)d_out;
  int nvox = in_sizes[0] / NG;  // 1,000,000
  int grid = (nvox + 255) / 256;
  hipLaunchKernelGGL(fa_kernel, dim3(grid), dim3(256), 0, stream,
                     dwi, mask, W, mdp, out, nvox);
}